// Round 1
// baseline (938.402 us; speedup 1.0000x reference)
//
#include <hip/hip_runtime.h>
#include <hip/hip_bf16.h>

#define BS 16
#define SEQ 4096
#define DIM 64
#define NH 8
#define CL 128
#define NC (SEQ/CL)       // 32
#define NPAIR (NH*BS)     // 128
#define QSTR 68           // padded LDS row stride (floats), 272B = 16B-aligned
#define PSTR 132          // P-buffer stride (floats)
#define TLDS_Q (CL*QSTR)  // 8704 floats per staged tile

__device__ __forceinline__ float dot4(float4 a, float4 b) {
    return a.x*b.x + a.y*b.y + a.z*b.z + a.w*b.w;
}

// ---------------- norms + per-batch max(norm^2) ----------------
__global__ __launch_bounds__(256) void norms_kernel(const float* __restrict__ q,
        const float* __restrict__ k, float* __restrict__ qn2, float* __restrict__ kn2,
        unsigned int* __restrict__ M2bits) {
    int blk = blockIdx.x;
    const int qblocks = BS*SEQ/64;
    bool is_q = blk < qblocks;
    int rowbase = (is_q ? blk : blk - qblocks) * 64;
    const float* src = is_q ? q : k;
    float* dst = is_q ? qn2 : kn2;
    int t = threadIdx.x;
    int sub = t & 3;
    int r = rowbase + (t >> 2);
    const float4* row4 = (const float4*)(src + (size_t)r*DIM) + sub*4;
    float s = 0.f;
    #pragma unroll
    for (int c2 = 0; c2 < 4; ++c2) {
        float4 vv = row4[c2];
        s += vv.x*vv.x + vv.y*vv.y + vv.z*vv.z + vv.w*vv.w;
    }
    s += __shfl_xor(s, 1);
    s += __shfl_xor(s, 2);
    if (sub == 0) dst[r] = s;
    __shared__ float red[256];
    red[t] = s;
    __syncthreads();
    #pragma unroll
    for (int o = 128; o > 0; o >>= 1) {
        if (t < o) red[t] = fmaxf(red[t], red[t + o]);
        __syncthreads();
    }
    if (t == 0) atomicMax(&M2bits[r / SEQ], __float_as_uint(red[0]));
}

// ---------------- E2LSH hashes ----------------
__global__ __launch_bounds__(256) void hash_kernel(const float* __restrict__ q,
        const float* __restrict__ k, const float* __restrict__ qn2,
        const float* __restrict__ kn2, const unsigned int* __restrict__ M2bits,
        const float* __restrict__ alpha, const float* __restrict__ beta,
        float* __restrict__ qh, float* __restrict__ kh) {
    int t = threadIdx.x;
    int sub = t & 3;
    int r = blockIdx.x * 64 + (t >> 2);
    const float4* q4 = (const float4*)(q + (size_t)r*DIM) + sub*4;
    const float4* k4 = (const float4*)(k + (size_t)r*DIM) + sub*4;
    float qa[NH], ka[NH];
    #pragma unroll
    for (int h = 0; h < NH; ++h) { qa[h] = 0.f; ka[h] = 0.f; }
    #pragma unroll
    for (int c2 = 0; c2 < 4; ++c2) {
        int d0 = sub*16 + c2*4;
        float4 qv = q4[c2], kv = k4[c2];
        #pragma unroll
        for (int h = 0; h < NH; ++h) {
            float a0 = alpha[(d0+0)*NH+h], a1 = alpha[(d0+1)*NH+h];
            float a2 = alpha[(d0+2)*NH+h], a3 = alpha[(d0+3)*NH+h];
            qa[h] += qv.x*a0 + qv.y*a1 + qv.z*a2 + qv.w*a3;
            ka[h] += kv.x*a0 + kv.y*a1 + kv.z*a2 + kv.w*a3;
        }
    }
    #pragma unroll
    for (int h = 0; h < NH; ++h) {
        qa[h] += __shfl_xor(qa[h], 1); qa[h] += __shfl_xor(qa[h], 2);
        ka[h] += __shfl_xor(ka[h], 1); ka[h] += __shfl_xor(ka[h], 2);
    }
    if (sub == 0) {
        int b = r / SEQ;
        float m2 = __uint_as_float(M2bits[b]);
        float qe = sqrtf(fmaxf(m2 - qn2[r], 0.f));
        float ke = sqrtf(fmaxf(m2 - kn2[r], 0.f));
        #pragma unroll
        for (int h = 0; h < NH; ++h) {
            qh[(size_t)h*BS*SEQ + r] = qa[h] + qe*alpha[DIM*NH + h] + beta[h];
            kh[(size_t)h*BS*SEQ + r] = ka[h] + ke*alpha[(DIM+1)*NH + h] + beta[h];
        }
    }
}

// ---------------- stable bitonic argsort (4096 per block) ----------------
__global__ __launch_bounds__(512) void sort_kernel(const float* __restrict__ qh,
        const float* __restrict__ kh, int* __restrict__ qpos, int* __restrict__ kpos) {
    __shared__ float sh[SEQ];
    __shared__ int si[SEQ];
    int blk = blockIdx.x;
    const float* src; int* dst;
    if (blk < NPAIR) { src = qh + (size_t)blk*SEQ; dst = qpos + (size_t)blk*SEQ; }
    else { src = kh + (size_t)(blk - NPAIR)*SEQ; dst = kpos + (size_t)(blk - NPAIR)*SEQ; }
    int t = threadIdx.x;
    for (int i = t; i < SEQ; i += 512) { sh[i] = src[i]; si[i] = i; }
    __syncthreads();
    for (int kk = 2; kk <= SEQ; kk <<= 1) {
        for (int j = kk >> 1; j > 0; j >>= 1) {
            #pragma unroll
            for (int w = 0; w < SEQ/512; ++w) {
                int i = t + w*512;
                int ixj = i ^ j;
                if (ixj > i) {
                    bool up = (i & kk) == 0;
                    float h1 = sh[i], h2 = sh[ixj];
                    int i1 = si[i], i2 = si[ixj];
                    bool gt = (h1 > h2) || (h1 == h2 && i1 > i2);
                    if (gt == up) { sh[i] = h2; sh[ixj] = h1; si[i] = i2; si[ixj] = i1; }
                }
            }
            __syncthreads();
        }
    }
    for (int i = t; i < SEQ; i += 512) dst[i] = si[i];
}

// ---------------- pass 1: per-cluster row logsumexp ----------------
__global__ __launch_bounds__(256) void lse_kernel(const float* __restrict__ q,
        const float* __restrict__ k, const int* __restrict__ qpos,
        const int* __restrict__ kpos, float* __restrict__ lse) {
    extern __shared__ float smem[];
    float* sq = smem;
    float* sk = smem + TLDS_Q;
    int* qp = (int*)(smem + 2*TLDS_Q);
    int* kp = qp + CL;
    int blk = blockIdx.x;
    int c = blk % NC;
    int hb = blk / NC;
    int b = hb % BS;
    int t = threadIdx.x;
    size_t posbase = (size_t)hb*SEQ + (size_t)c*CL;
    if (t < CL) qp[t] = qpos[posbase + t];
    else kp[t - CL] = kpos[posbase + (t - CL)];
    __syncthreads();
    for (int i = t; i < 2*CL*16; i += 256) {
        int idx = i & (CL*16 - 1);
        int r = idx >> 4, d4 = idx & 15;
        if (i < CL*16) {
            float4 vv = ((const float4*)(q + ((size_t)b*SEQ + qp[r])*DIM))[d4];
            *(float4*)(sq + r*QSTR + d4*4) = vv;
        } else {
            float4 vv = ((const float4*)(k + ((size_t)b*SEQ + kp[r])*DIM))[d4];
            *(float4*)(sk + r*QSTR + d4*4) = vv;
        }
    }
    __syncthreads();
    int tx = t & 15, ty = t >> 4;
    float acc[8][8] = {};
    for (int d = 0; d < DIM; d += 4) {
        float4 qv[8], kv[8];
        #pragma unroll
        for (int i = 0; i < 8; ++i) qv[i] = *(const float4*)(sq + (ty + 16*i)*QSTR + d);
        #pragma unroll
        for (int j = 0; j < 8; ++j) kv[j] = *(const float4*)(sk + (tx + 16*j)*QSTR + d);
        #pragma unroll
        for (int i = 0; i < 8; ++i)
            #pragma unroll
            for (int j = 0; j < 8; ++j)
                acc[i][j] += dot4(qv[i], kv[j]);
    }
    #pragma unroll
    for (int i = 0; i < 8; ++i) {
        int row = ty + 16*i;
        float m = acc[i][0];
        #pragma unroll
        for (int j = 1; j < 8; ++j) m = fmaxf(m, acc[i][j]);
        #pragma unroll
        for (int o = 1; o < 16; o <<= 1) m = fmaxf(m, __shfl_xor(m, o));
        float ssum = 0.f;
        #pragma unroll
        for (int j = 0; j < 8; ++j) ssum += expf(acc[i][j] - m);
        #pragma unroll
        for (int o = 1; o < 16; o <<= 1) ssum += __shfl_xor(ssum, o);
        if (tx == 0) lse[(size_t)hb*SEQ + qp[row]] = m + logf(ssum);
    }
}

// ---------------- Z = logsumexp over hash rounds ----------------
__global__ __launch_bounds__(256) void z_kernel(const float* __restrict__ lse,
        float* __restrict__ Z) {
    int i = blockIdx.x * 256 + threadIdx.x;
    float vals[NH];
    float m = -1e30f;
    #pragma unroll
    for (int h = 0; h < NH; ++h) {
        vals[h] = lse[(size_t)h*BS*SEQ + i];
        m = fmaxf(m, vals[h]);
    }
    float s = 0.f;
    #pragma unroll
    for (int h = 0; h < NH; ++h) s += expf(vals[h] - m);
    Z[i] = m + logf(s);
}

// ---------------- pass 2: exp(QK^T - Z) @ V, atomic scatter ----------------
__global__ __launch_bounds__(256) void attn_kernel(const float* __restrict__ q,
        const float* __restrict__ k, const float* __restrict__ v,
        const int* __restrict__ qpos, const int* __restrict__ kpos,
        const float* __restrict__ Z, float* __restrict__ out) {
    extern __shared__ float smem[];
    float* sq = smem;
    float* sv = smem + 2*TLDS_Q;
    int* qp = (int*)(smem + 3*TLDS_Q);
    int* kp = qp + CL;
    float* zq = (float*)(kp + CL);
    float* pbuf = smem;  // overlays sq+sk after QK phase (16896 <= 17408 floats)
    int blk = blockIdx.x;
    int c = blk % NC;
    int hb = blk / NC;
    int b = hb % BS;
    int t = threadIdx.x;
    size_t posbase = (size_t)hb*SEQ + (size_t)c*CL;
    if (t < CL) qp[t] = qpos[posbase + t];
    else kp[t - CL] = kpos[posbase + (t - CL)];
    __syncthreads();
    if (t < CL) zq[t] = Z[(size_t)b*SEQ + qp[t]];
    for (int i = t; i < 3*CL*16; i += 256) {
        int idx = i & (CL*16 - 1);
        int r = idx >> 4, d4 = idx & 15;
        int which = i >> 11;
        const float* src = (which == 0) ? (q + ((size_t)b*SEQ + qp[r])*DIM)
                         : (which == 1) ? (k + ((size_t)b*SEQ + kp[r])*DIM)
                                        : (v + ((size_t)b*SEQ + kp[r])*DIM);
        float4 vv = ((const float4*)src)[d4];
        *(float4*)(smem + which*TLDS_Q + r*QSTR + d4*4) = vv;
    }
    __syncthreads();
    int tx = t & 15, ty = t >> 4;
    float acc[8][8] = {};
    {
        const float* sk = smem + TLDS_Q;
        for (int d = 0; d < DIM; d += 4) {
            float4 qv[8], kv[8];
            #pragma unroll
            for (int i = 0; i < 8; ++i) qv[i] = *(const float4*)(sq + (ty + 16*i)*QSTR + d);
            #pragma unroll
            for (int j = 0; j < 8; ++j) kv[j] = *(const float4*)(sk + (tx + 16*j)*QSTR + d);
            #pragma unroll
            for (int i = 0; i < 8; ++i)
                #pragma unroll
                for (int j = 0; j < 8; ++j)
                    acc[i][j] += dot4(qv[i], kv[j]);
        }
    }
    #pragma unroll
    for (int i = 0; i < 8; ++i) {
        float zr = zq[ty + 16*i];
        #pragma unroll
        for (int j = 0; j < 8; ++j) acc[i][j] = expf(acc[i][j] - zr);
    }
    __syncthreads();  // all threads done reading sq/sk
    #pragma unroll
    for (int i = 0; i < 8; ++i)
        #pragma unroll
        for (int j = 0; j < 8; ++j)
            pbuf[(ty + 16*i)*PSTR + tx + 16*j] = acc[i][j];
    __syncthreads();
    float o[8][4] = {};
    for (int kk = 0; kk < CL; kk += 4) {
        float4 pv[8];
        #pragma unroll
        for (int i = 0; i < 8; ++i) pv[i] = *(const float4*)(pbuf + (ty + 16*i)*PSTR + kk);
        float sb[4][4];
        #pragma unroll
        for (int kq = 0; kq < 4; ++kq)
            #pragma unroll
            for (int jj = 0; jj < 4; ++jj) sb[kq][jj] = sv[(kk + kq)*QSTR + tx + 16*jj];
        #pragma unroll
        for (int i = 0; i < 8; ++i)
            #pragma unroll
            for (int jj = 0; jj < 4; ++jj)
                o[i][jj] += pv[i].x*sb[0][jj] + pv[i].y*sb[1][jj]
                          + pv[i].z*sb[2][jj] + pv[i].w*sb[3][jj];
    }
    #pragma unroll
    for (int i = 0; i < 8; ++i) {
        size_t orow = ((size_t)b*SEQ + qp[ty + 16*i])*DIM;
        #pragma unroll
        for (int jj = 0; jj < 4; ++jj)
            atomicAdd(out + orow + tx + 16*jj, o[i][jj]);
    }
}

extern "C" void kernel_launch(void* const* d_in, const int* in_sizes, int n_in,
                              void* d_out, int out_size, void* d_ws, size_t ws_size,
                              hipStream_t stream) {
    const float* q     = (const float*)d_in[0];
    const float* k     = (const float*)d_in[1];
    const float* v     = (const float*)d_in[2];
    const float* alpha = (const float*)d_in[3];
    const float* beta  = (const float*)d_in[4];
    float* out = (float*)d_out;

    // workspace layout (floats): ~11 MB total
    float* ws   = (float*)d_ws;
    float* M2   = ws;                        // 16 (padded to 64)
    float* qn2  = ws + 64;                   // BS*SEQ
    float* kn2  = qn2 + BS*SEQ;              // BS*SEQ
    float* qh   = kn2 + BS*SEQ;              // NH*BS*SEQ
    float* kh   = qh + (size_t)NH*BS*SEQ;    // NH*BS*SEQ
    int*   qpos = (int*)(kh + (size_t)NH*BS*SEQ);  // NH*BS*SEQ
    int*   kpos = qpos + (size_t)NH*BS*SEQ;        // NH*BS*SEQ
    float* lse  = (float*)(kpos + (size_t)NH*BS*SEQ); // NH*BS*SEQ
    float* Z    = lse + (size_t)NH*BS*SEQ;         // BS*SEQ

    hipMemsetAsync(M2, 0, 64*sizeof(float), stream);
    hipMemsetAsync(out, 0, (size_t)out_size*sizeof(float), stream);

    norms_kernel<<<2*BS*SEQ/64, 256, 0, stream>>>(q, k, qn2, kn2, (unsigned int*)M2);
    hash_kernel<<<BS*SEQ/64, 256, 0, stream>>>(q, k, qn2, kn2, (const unsigned int*)M2,
                                               alpha, beta, qh, kh);
    sort_kernel<<<2*NPAIR, 512, 0, stream>>>(qh, kh, qpos, kpos);

    const int lse_lds  = (2*TLDS_Q + 2*CL)*sizeof(float);          // 70656 B
    const int attn_lds = (3*TLDS_Q + 3*CL)*sizeof(float);          // 105984 B
    lse_kernel<<<NH*BS*NC, 256, lse_lds, stream>>>(q, k, qpos, kpos, lse);
    z_kernel<<<BS*SEQ/256, 256, 0, stream>>>(lse, Z);
    attn_kernel<<<NH*BS*NC, 256, attn_lds, stream>>>(q, k, v, qpos, kpos, Z, out);
}